// Round 13
// baseline (49.764 us; speedup 1.0000x reference)
//
#include <hip/hip_runtime.h>
#include <math.h>

static constexpr int NA = 9;
static constexpr int NH = 128;
static constexpr int NW = 128;
static constexpr int NC = 4;
static constexpr int CH = 6 + NC;      // 10 channels
static constexpr int TCOLS = 13 + NC;  // 17 target columns
static constexpr float SCALE_INV = 1.0f / 16.0f;
static constexpr int NBG = 2048;       // k_bg grid
static constexpr int SCAN_STRIDE = 16; // floats per scan-block partial record
static constexpr int HSLOTS = 128;     // LDS hash table slots (>= 2*T)

typedef float f4 __attribute__((ext_vector_type(4)));  // NT-loadable vec4

// ANCHORS_PX / 16
__constant__ float c_aw[NA] = {1.f, 2.f, 4.f, 8.f, 16.f, 2.f, 4.f, 8.f, 4.f};
__constant__ float c_ah[NA] = {1.f, 2.f, 4.f, 8.f, 16.f, 4.f, 2.f, 4.f, 8.f};

// scan partial slots: 0 corrNum, 1 corrDen, 2 maskCnt, 3 lx, 4 ly, 5 lw,
// 6 lh, 7 lcls, 8 lconfM, 9 nGT, 10 nCor
static constexpr int NSLOT = 11;

__device__ __forceinline__ float bcef(float x, float z) {
    return fmaxf(x, 0.f) - x * z + log1pf(expf(-fabsf(x)));
}
__device__ __forceinline__ float invtanh(float y) {
    if (y <= -1.f) return -2.f;
    if (y >= 1.f) return 2.f;
    return 0.5f * logf((1.f + y) / (1.f - y));
}
__device__ __forceinline__ float wredf(float v) {
#pragma unroll
    for (int o = 32; o; o >>= 1) v += __shfl_down(v, o, 64);
    return v;
}
__device__ __forceinline__ double wredd(double v) {
#pragma unroll
    for (int o = 32; o; o >>= 1) v += __shfl_down(v, o, 64);
    return v;
}

// Dense background pass: lane-contiguous float4 stream (copy-kernel shape).
// Thread handles 5 vec4s (= 80 B = 2 cells) per iteration at offsets
// base + tid + 256k. All strides are multiples of 1280 vec4s (5120 B,
// = 0 mod 40 B cell), so the channel residue r_k = (4*tid + 4k) % 10 is
// loop-invariant: conf at [0] when r==0, [2] when r==8, else no conf.
// No modulo / no select chain in the hot loop.
// Block 0 zeroes the rendezvous counter for k_scanfin. No memset dispatch.
__global__ __launch_bounds__(256) void k_bg(const f4* __restrict__ pred4,
                                            float2* __restrict__ bgPart,
                                            unsigned int* __restrict__ doneCtr,
                                            int n4) {
    if (blockIdx.x == 0 && threadIdx.x == 0) *doneCtr = 0u;
    __shared__ float sdat[2][4];
    const int tid = threadIdx.x;
    int rk[5];
#pragma unroll
    for (int k = 0; k < 5; k++) rk[k] = (4 * tid + 4 * k) % 10;

    float s0 = 0.f, npos = 0.f;
    const int iterStride = NBG * 256 * 5;            // vec4s per grid iter
    for (int blockBase = blockIdx.x * (256 * 5); blockBase < n4;
         blockBase += iterStride) {
#pragma unroll
        for (int k = 0; k < 5; k++) {
            int i = blockBase + tid + 256 * k;
            if ((rk[k] == 0 || rk[k] == 8) && i < n4) {
                f4 v = __builtin_nontemporal_load(&pred4[i]);
                float conf = (rk[k] == 0) ? v[0] : v[2];
                s0 += fmaxf(conf, 0.f) + log1pf(expf(-fabsf(conf)));
                npos += (conf > 0.f) ? 1.f : 0.f;
            } else if (i < n4) {
                f4 v = __builtin_nontemporal_load(&pred4[i]);
                // keep the load live so the wave streams the full line
                asm volatile("" :: "v"(v[0]));
            }
        }
    }
    s0 = wredf(s0); npos = wredf(npos);
    int wid = tid >> 6;
    if ((tid & 63) == 0) { sdat[0][wid] = s0; sdat[1][wid] = npos; }
    __syncthreads();
    if (tid == 0) {
        float a0 = sdat[0][0] + sdat[0][1] + sdat[0][2] + sdat[0][3];
        float a1 = sdat[1][0] + sdat[1][1] + sdat[1][2] + sdat[1][3];
        bgPart[blockIdx.x] = make_float2(a0, a1);
    }
}

// One block (4 waves) per batch; scan via LDS hash + atomicMax priority
// (pri = 2*t + (best?1:0) == reference write order). Runs AFTER k_bg in the
// stream, so bgPart is complete and doneCtr is zeroed; the LAST of the nB
// blocks (16-block rendezvous -- ~1 us at this count) finalizes.
__global__ __launch_bounds__(256) void k_scanfin(
    const float* __restrict__ pred, const float* __restrict__ tgt,
    const int* __restrict__ tsz, float* __restrict__ scanPart,
    const float2* __restrict__ bgPart, unsigned int* __restrict__ doneCtr,
    float* __restrict__ out, int nB, int T, double totalCells) {
    const int b = blockIdx.x;
    const int tid = threadIdx.x;
    const int lane = tid & 63;
    const int wave = tid >> 6;

    __shared__ int sPack[64], sTl[64], sSlot[64];
    __shared__ float sTx[64], sTy[64], sTw[64], sTh[64];
    __shared__ int sKey[HSLOTS];
    __shared__ int sPri[HSLOTS * NA];   // max over ALL touches
    __shared__ int sBest[HSLOTS * NA];  // max over BEST touches only
    __shared__ float sAccW[4][NSLOT];
    __shared__ int sFlag;

    for (int i = tid; i < HSLOTS; i += 256) sKey[i] = -1;
    for (int i = tid; i < HSLOTS * NA; i += 256) { sPri[i] = -1; sBest[i] = -1; }
    if (tid < 64) sPack[tid] = 0;

    const int ts = tsz[b];
    float fGT = 0.f, fCor = 0.f;

    // ---- Phase A: thread t handles target t, spread across all 4 waves ----
    if (tid < T) {
        const int t = tid;
        const float* row = tgt + (size_t)(b * T + t) * TCOLS;
        float gx = row[0] * SCALE_INV, gy = row[1] * SCALE_INV;
        float gh = row[3] * SCALE_INV, gw = row[4] * SCALE_INV;
        int valid = (t < ts) && (gw != 0.f) && (gh != 0.f);
        int gi = (int)gx; gi = gi < 0 ? 0 : (gi > NW - 1 ? NW - 1 : gi);
        int gj = (int)gy; gj = gj < 0 ? 0 : (gj > NH - 1 ? NH - 1 : gj);

        float bestIou = -1.f; int best = 0; int ign = 0;
#pragma unroll
        for (int a = 0; a < NA; a++) {
            float aw = c_aw[a], ah = c_ah[a];
            float inter = (fminf(gw, aw) + 1.f) * (fminf(gh, ah) + 1.f);
            float uni = (gw + 1.f) * (gh + 1.f) + (aw + 1.f) * (ah + 1.f) - inter + 1e-16f;
            float iou = inter / uni;
            if (iou > 0.5f) ign |= (1 << a);
            if (iou > bestIou) { bestIou = iou; best = a; }
        }
        sPack[t] = (valid ? 1 : 0) | (best << 1) | (ign << 5) | ((gj * NW + gi) << 14);
        sTx[t] = invtanh(gx - ((float)gi + 0.5f));
        sTy[t] = invtanh(gy - ((float)gj + 0.5f));
        sTw[t] = logf(gw / c_aw[best] + 1e-16f);
        sTh[t] = logf(gh / c_ah[best] + 1e-16f);

        float cc0 = row[13], cc1 = row[14], cc2 = row[15], cc3 = row[16];
        int tl = 0; float cmax = cc0;
        if (cc1 > cmax) { cmax = cc1; tl = 1; }
        if (cc2 > cmax) { cmax = cc2; tl = 2; }
        if (cc3 > cmax) { cmax = cc3; tl = 3; }
        sTl[t] = tl;

        if (valid) {
            fGT = 1.f;
            const float* p = pred + ((((size_t)b * NA + best) * NH + gj) * NW + gi) * CH;
            float p0 = p[0];
            float px = tanhf(p[1]) + 0.5f + (float)gi;
            float py = tanhf(p[2]) + 0.5f + (float)gj;
            float pw = expf(p[5]) * c_aw[best];
            float ph = expf(p[4]) * c_ah[best];
            float b1x1 = gx - gw, b1x2 = gx + gw, b1y1 = gy - gh, b1y2 = gy + gh;
            float b2x1 = px - pw, b2x2 = px + pw, b2y1 = py - ph, b2y2 = py + ph;
            float iw = fmaxf(fminf(b1x2, b2x2) - fmaxf(b1x1, b2x1) + 1.f, 0.f);
            float ih = fmaxf(fminf(b1y2, b2y2) - fmaxf(b1y1, b2y1) + 1.f, 0.f);
            float inter = iw * ih;
            float a1 = (b1x2 - b1x1 + 1.f) * (b1y2 - b1y1 + 1.f);
            float a2 = (b2x2 - b2x1 + 1.f) * (b2y2 - b2y1 + 1.f);
            float iou = inter / (a1 + a2 - inter + 1e-16f);
            float q0 = p[6], q1 = p[7], q2 = p[8], q3 = p[9];
            int pl = 0; float qm = q0;
            if (q1 > qm) { qm = q1; pl = 1; }
            if (q2 > qm) { qm = q2; pl = 2; }
            if (q3 > qm) { qm = q3; pl = 3; }
            if (iou > 0.5f && pl == tl && p0 > 0.f) fCor = 1.f;
        }
    }
    __syncthreads();

    // ---- Insert: one thread per valid target, CAS-probe cell ----
    if (tid < T) {
        int p = sPack[tid];
        if (p & 1) {
            int cell = p >> 14;
            int slot = cell & (HSLOTS - 1);
            while (true) {
                int old = atomicCAS(&sKey[slot], -1, cell);
                if (old == -1 || old == cell) break;
                slot = (slot + 1) & (HSLOTS - 1);
            }
            sSlot[tid] = slot;
        }
    }
    __syncthreads();

    // ---- Touch: one thread per (t, a); priority max into table ----
    for (int item = tid; item < T * NA; item += 256) {
        int t = item / NA, a = item - t * NA;
        int p = sPack[t];
        if (!(p & 1)) continue;
        int slot = sSlot[t];
        int best = (p >> 1) & 0xF;
        if (a == best) {
            atomicMax(&sPri[slot * NA + a], 2 * t + 1);
            atomicMax(&sBest[slot * NA + a], 2 * t + 1);
        } else if ((p >> (5 + a)) & 1) {
            atomicMax(&sPri[slot * NA + a], 2 * t);
        }
    }
    __syncthreads();

    // ---- Resolve: one pass over table entries; C1 + C2 fused ----
    float corrNum = 0.f, corrDen = 0.f, lconfM = 0.f, maskCnt = 0.f;
    float lx = 0.f, ly = 0.f, lw = 0.f, lh = 0.f, lcls = 0.f;
    for (int it = tid; it < HSLOTS * NA; it += 256) {
        int slot = it / NA, a = it - slot * NA;
        int cell = sKey[slot];
        if (cell < 0) continue;
        int pm = sPri[it];
        if (pm < 0) continue;                   // (cell,a) untouched
        int bm = sBest[it];
        const float* pp = pred + ((size_t)(b * NA + a) * (NH * NW) + cell) * CH;
        float conf = pp[0];
        float bce0 = bcef(conf, 0.f);
        if (bm >= 0) {                          // masked: mask=1, tconf=1
            float cm = (float)(pm & 1);         // last-writer parity
            float cmf = cm - 1.f;               // 0 or -1
            float bce1 = bcef(conf, 1.f);
            corrNum += bce1 * cmf - bce0;
            corrDen += cmf - 1.f;
            lconfM += bce1;
            maskCnt += 1.f;
            int t = bm >> 1;                    // last best writer
            float dx = pp[1] - sTx[t], dy = pp[2] - sTy[t];
            float dw = pp[5] - sTw[t], dh = pp[4] - sTh[t];
            lx += dx * dx; ly += dy * dy; lw += dw * dw; lh += dh * dh;
            float q0 = pp[6], q1 = pp[7], q2 = pp[8], q3 = pp[9];
            float m = fmaxf(fmaxf(q0, q1), fmaxf(q2, q3));
            float lse = m + logf(expf(q0 - m) + expf(q1 - m) + expf(q2 - m) + expf(q3 - m));
            lcls += lse - pp[6 + sTl[t]];
        } else {                                // ignore-only: cmf = 0
            corrNum -= bce0;
            corrDen -= 1.f;
        }
    }

    float v;
    v = wredf(corrNum); if (lane == 0) sAccW[wave][0] = v;
    v = wredf(corrDen); if (lane == 0) sAccW[wave][1] = v;
    v = wredf(maskCnt); if (lane == 0) sAccW[wave][2] = v;
    v = wredf(lx);      if (lane == 0) sAccW[wave][3] = v;
    v = wredf(ly);      if (lane == 0) sAccW[wave][4] = v;
    v = wredf(lw);      if (lane == 0) sAccW[wave][5] = v;
    v = wredf(lh);      if (lane == 0) sAccW[wave][6] = v;
    v = wredf(lcls);    if (lane == 0) sAccW[wave][7] = v;
    v = wredf(lconfM);  if (lane == 0) sAccW[wave][8] = v;
    v = wredf(fGT);     if (lane == 0) sAccW[wave][9] = v;
    v = wredf(fCor);    if (lane == 0) sAccW[wave][10] = v;
    __syncthreads();
    if (tid < NSLOT) {
        float s = sAccW[0][tid] + sAccW[1][tid] + sAccW[2][tid] + sAccW[3][tid];
        scanPart[b * SCAN_STRIDE + tid] = s;
    }

    // ---- 16-block rendezvous; last block finalizes ----
    __syncthreads();
    if (tid == 0) {
        __threadfence();  // release scanPart
        unsigned int old = atomicAdd(doneCtr, 1u);
        sFlag = (old == (unsigned int)(nB - 1)) ? 1 : 0;
    }
    __syncthreads();
    if (sFlag) {
        __threadfence();  // acquire
        __shared__ double dR[2][4];
        __shared__ double dScan[NSLOT];
        double s0 = 0.0, np = 0.0;
        for (int i = tid; i < NBG; i += 256) {
            float2 p2 = bgPart[i];
            s0 += (double)p2.x; np += (double)p2.y;
        }
        s0 = wredd(s0); np = wredd(np);
        if (lane == 0) { dR[0][wave] = s0; dR[1][wave] = np; }
        if (tid < NSLOT) {
            double s = 0.0;
            for (int b2 = 0; b2 < nB; b2++) s += (double)scanPart[b2 * SCAN_STRIDE + tid];
            dScan[tid] = s;
        }
        __syncthreads();
        if (tid == 0) {
            double S0 = dR[0][0] + dR[0][1] + dR[0][2] + dR[0][3];
            double nProp = dR[1][0] + dR[1][1] + dR[1][2] + dR[1][3];
            double corrNum2 = dScan[0], corrDen2 = dScan[1], maskCnt2 = dScan[2];
            double lx2 = dScan[3], ly2 = dScan[4], lw2 = dScan[5], lh2 = dScan[6];
            double lcls2 = dScan[7], lconfM2 = dScan[8], nGT = dScan[9], nCor = dScan[10];

            double msum = fmax(maskCnt2, 1.0);
            double cden = fmax(totalCells + corrDen2, 1.0);
            double loss_conf = 1.25 * (S0 + corrNum2) / cden + lconfM2 / msum;
            double lx_ = lx2 / msum, ly_ = ly2 / msum, lw_ = lw2 / msum, lh_ = lh2 / msum;
            double lcls_ = (lcls2 / msum) / (double)nB;
            double coord = lx_ + ly_ + lw_ + lh_;
            double loss = coord + loss_conf + lcls_;
            double recall = (nGT > 0.0) ? nCor / fmax(nGT, 1.0) : 1.0;
            double precision = (nProp > 0.0) ? nCor / fmax(nProp, 1.0) : 1.0;

            out[0] = (float)loss;
            out[1] = (float)coord;
            out[2] = (float)loss_conf;
            out[3] = (float)lcls_;
            out[4] = (float)recall;
            out[5] = (float)precision;
        }
    }
}

extern "C" void kernel_launch(void* const* d_in, const int* in_sizes, int n_in,
                              void* d_out, int out_size, void* d_ws, size_t ws_size,
                              hipStream_t stream) {
    const float* pred = (const float*)d_in[0];
    const float* tgt = (const float*)d_in[1];
    const int* tsz = (const int*)d_in[2];
    int nB = in_sizes[2];
    int T = in_sizes[1] / (nB * TCOLS);
    long long total = (long long)nB * NA * NH * NW;
    int n4 = (int)(total * CH / 4);

    // d_ws layout: [scanPart: nB*SCAN_STRIDE floats][bgPart: NBG float2][doneCtr]
    float* scanPart = (float*)d_ws;
    float2* bgPart = (float2*)((char*)d_ws + (size_t)nB * SCAN_STRIDE * sizeof(float));
    unsigned int* doneCtr =
        (unsigned int*)((char*)bgPart + (size_t)NBG * sizeof(float2));
    float* out = (float*)d_out;

    hipLaunchKernelGGL(k_bg, dim3(NBG), dim3(256), 0, stream, (const f4*)pred,
                       bgPart, doneCtr, n4);
    hipLaunchKernelGGL(k_scanfin, dim3(nB), dim3(256), 0, stream, pred, tgt, tsz,
                       scanPart, bgPart, doneCtr, out, nB, T, (double)total);
}

// Round 14
// 39.021 us; speedup vs baseline: 1.2753x; 1.2753x over previous
//
#include <hip/hip_runtime.h>
#include <math.h>

static constexpr int NA = 9;
static constexpr int NH = 128;
static constexpr int NW = 128;
static constexpr int NC = 4;
static constexpr int CH = 6 + NC;      // 10 channels
static constexpr int TCOLS = 13 + NC;  // 17 target columns
static constexpr float SCALE_INV = 1.0f / 16.0f;
static constexpr int NBG = 2048;       // k_bg grid
static constexpr int SCAN_STRIDE = 16; // floats per scan-block partial record
static constexpr int HSLOTS = 128;     // LDS hash table slots (>= 2*T)

// ANCHORS_PX / 16
__constant__ float c_aw[NA] = {1.f, 2.f, 4.f, 8.f, 16.f, 2.f, 4.f, 8.f, 4.f};
__constant__ float c_ah[NA] = {1.f, 2.f, 4.f, 8.f, 16.f, 4.f, 2.f, 4.f, 8.f};

// scan partial slots: 0 corrNum, 1 corrDen, 2 maskCnt, 3 lx, 4 ly, 5 lw,
// 6 lh, 7 lcls, 8 lconfM, 9 nGT, 10 nCor
static constexpr int NSLOT = 11;

__device__ __forceinline__ float bcef(float x, float z) {
    return fmaxf(x, 0.f) - x * z + log1pf(expf(-fabsf(x)));
}
__device__ __forceinline__ float invtanh(float y) {
    if (y <= -1.f) return -2.f;
    if (y >= 1.f) return 2.f;
    return 0.5f * logf((1.f + y) / (1.f - y));
}
__device__ __forceinline__ float wredf(float v) {
#pragma unroll
    for (int o = 32; o; o >>= 1) v += __shfl_down(v, o, 64);
    return v;
}
__device__ __forceinline__ double wredd(double v) {
#pragma unroll
    for (int o = 32; o; o >>= 1) v += __shfl_down(v, o, 64);
    return v;
}

// Dense background pass: nontemporal scalar gather of ONLY the conf channel
// (stride 10 floats). Every 64 B line holds a conf value, so line traffic
// equals a full stream with 2.5x fewer load instructions than a float4
// stream (R13 measured the dense-stream shape 10 us slower). NT hint avoids
// L2/L3 allocate churn on the ~half of pred that misses L3 (R7 vs R10).
// Block 0 zeroes the rendezvous counter for k_scanfin (runs after us
// in-stream); kernel-boundary flush makes it visible. No memset dispatch
// (a 32 B fillBuffer costs ~55 us of fixed dispatch time, R9).
__global__ __launch_bounds__(256) void k_bg(const float* __restrict__ pred,
                                            float2* __restrict__ bgPart,
                                            unsigned int* __restrict__ doneCtr,
                                            int nCells) {
    if (blockIdx.x == 0 && threadIdx.x == 0) *doneCtr = 0u;
    __shared__ float sdat[2][4];
    float s0 = 0.f, npos = 0.f;
    const int stride = gridDim.x * blockDim.x;
    int c = blockIdx.x * blockDim.x + threadIdx.x;
    // 3-way unrolled grid-stride: 3 independent loads in flight per thread
    for (; c + 2 * stride < nCells; c += 3 * stride) {
        float c0 = __builtin_nontemporal_load(&pred[(size_t)c * CH]);
        float c1 = __builtin_nontemporal_load(&pred[(size_t)(c + stride) * CH]);
        float c2 = __builtin_nontemporal_load(&pred[(size_t)(c + 2 * stride) * CH]);
        s0 += fmaxf(c0, 0.f) + log1pf(expf(-fabsf(c0)));
        s0 += fmaxf(c1, 0.f) + log1pf(expf(-fabsf(c1)));
        s0 += fmaxf(c2, 0.f) + log1pf(expf(-fabsf(c2)));
        npos += (c0 > 0.f) ? 1.f : 0.f;
        npos += (c1 > 0.f) ? 1.f : 0.f;
        npos += (c2 > 0.f) ? 1.f : 0.f;
    }
    for (; c < nCells; c += stride) {
        float cv = __builtin_nontemporal_load(&pred[(size_t)c * CH]);
        s0 += fmaxf(cv, 0.f) + log1pf(expf(-fabsf(cv)));
        npos += (cv > 0.f) ? 1.f : 0.f;
    }
    s0 = wredf(s0); npos = wredf(npos);
    int wid = threadIdx.x >> 6;
    if ((threadIdx.x & 63) == 0) { sdat[0][wid] = s0; sdat[1][wid] = npos; }
    __syncthreads();
    if (threadIdx.x == 0) {
        float a0 = sdat[0][0] + sdat[0][1] + sdat[0][2] + sdat[0][3];
        float a1 = sdat[1][0] + sdat[1][1] + sdat[1][2] + sdat[1][3];
        bgPart[blockIdx.x] = make_float2(a0, a1);
    }
}

// One block (4 waves) per batch; scan via LDS hash + atomicMax priority
// (pri = 2*t + (best?1:0) == reference write order). Runs AFTER k_bg in the
// stream, so bgPart is complete and doneCtr is zeroed; the LAST of the nB
// blocks (16-block rendezvous -- ~1 us at this count; 2000-block rendezvous
// measured ~105 us, R8) finalizes in doubles and writes out.
__global__ __launch_bounds__(256) void k_scanfin(
    const float* __restrict__ pred, const float* __restrict__ tgt,
    const int* __restrict__ tsz, float* __restrict__ scanPart,
    const float2* __restrict__ bgPart, unsigned int* __restrict__ doneCtr,
    float* __restrict__ out, int nB, int T, double totalCells) {
    const int b = blockIdx.x;
    const int tid = threadIdx.x;
    const int lane = tid & 63;
    const int wave = tid >> 6;

    __shared__ int sPack[64], sTl[64], sSlot[64];
    __shared__ float sTx[64], sTy[64], sTw[64], sTh[64];
    __shared__ int sKey[HSLOTS];
    __shared__ int sPri[HSLOTS * NA];   // max over ALL touches
    __shared__ int sBest[HSLOTS * NA];  // max over BEST touches only
    __shared__ float sAccW[4][NSLOT];
    __shared__ int sFlag;

    for (int i = tid; i < HSLOTS; i += 256) sKey[i] = -1;
    for (int i = tid; i < HSLOTS * NA; i += 256) { sPri[i] = -1; sBest[i] = -1; }
    if (tid < 64) sPack[tid] = 0;

    const int ts = tsz[b];
    float fGT = 0.f, fCor = 0.f;

    // ---- Phase A: thread t handles target t, spread across all 4 waves ----
    if (tid < T) {
        const int t = tid;
        const float* row = tgt + (size_t)(b * T + t) * TCOLS;
        float gx = row[0] * SCALE_INV, gy = row[1] * SCALE_INV;
        float gh = row[3] * SCALE_INV, gw = row[4] * SCALE_INV;
        int valid = (t < ts) && (gw != 0.f) && (gh != 0.f);
        int gi = (int)gx; gi = gi < 0 ? 0 : (gi > NW - 1 ? NW - 1 : gi);
        int gj = (int)gy; gj = gj < 0 ? 0 : (gj > NH - 1 ? NH - 1 : gj);

        float bestIou = -1.f; int best = 0; int ign = 0;
#pragma unroll
        for (int a = 0; a < NA; a++) {
            float aw = c_aw[a], ah = c_ah[a];
            float inter = (fminf(gw, aw) + 1.f) * (fminf(gh, ah) + 1.f);
            float uni = (gw + 1.f) * (gh + 1.f) + (aw + 1.f) * (ah + 1.f) - inter + 1e-16f;
            float iou = inter / uni;
            if (iou > 0.5f) ign |= (1 << a);
            if (iou > bestIou) { bestIou = iou; best = a; }
        }
        sPack[t] = (valid ? 1 : 0) | (best << 1) | (ign << 5) | ((gj * NW + gi) << 14);
        sTx[t] = invtanh(gx - ((float)gi + 0.5f));
        sTy[t] = invtanh(gy - ((float)gj + 0.5f));
        sTw[t] = logf(gw / c_aw[best] + 1e-16f);
        sTh[t] = logf(gh / c_ah[best] + 1e-16f);

        float cc0 = row[13], cc1 = row[14], cc2 = row[15], cc3 = row[16];
        int tl = 0; float cmax = cc0;
        if (cc1 > cmax) { cmax = cc1; tl = 1; }
        if (cc2 > cmax) { cmax = cc2; tl = 2; }
        if (cc3 > cmax) { cmax = cc3; tl = 3; }
        sTl[t] = tl;

        if (valid) {
            fGT = 1.f;
            const float* p = pred + ((((size_t)b * NA + best) * NH + gj) * NW + gi) * CH;
            float p0 = p[0];
            float px = tanhf(p[1]) + 0.5f + (float)gi;
            float py = tanhf(p[2]) + 0.5f + (float)gj;
            float pw = expf(p[5]) * c_aw[best];
            float ph = expf(p[4]) * c_ah[best];
            float b1x1 = gx - gw, b1x2 = gx + gw, b1y1 = gy - gh, b1y2 = gy + gh;
            float b2x1 = px - pw, b2x2 = px + pw, b2y1 = py - ph, b2y2 = py + ph;
            float iw = fmaxf(fminf(b1x2, b2x2) - fmaxf(b1x1, b2x1) + 1.f, 0.f);
            float ih = fmaxf(fminf(b1y2, b2y2) - fmaxf(b1y1, b2y1) + 1.f, 0.f);
            float inter = iw * ih;
            float a1 = (b1x2 - b1x1 + 1.f) * (b1y2 - b1y1 + 1.f);
            float a2 = (b2x2 - b2x1 + 1.f) * (b2y2 - b2y1 + 1.f);
            float iou = inter / (a1 + a2 - inter + 1e-16f);
            float q0 = p[6], q1 = p[7], q2 = p[8], q3 = p[9];
            int pl = 0; float qm = q0;
            if (q1 > qm) { qm = q1; pl = 1; }
            if (q2 > qm) { qm = q2; pl = 2; }
            if (q3 > qm) { qm = q3; pl = 3; }
            if (iou > 0.5f && pl == tl && p0 > 0.f) fCor = 1.f;
        }
    }
    __syncthreads();

    // ---- Insert: one thread per valid target, CAS-probe cell ----
    if (tid < T) {
        int p = sPack[tid];
        if (p & 1) {
            int cell = p >> 14;
            int slot = cell & (HSLOTS - 1);
            while (true) {
                int old = atomicCAS(&sKey[slot], -1, cell);
                if (old == -1 || old == cell) break;
                slot = (slot + 1) & (HSLOTS - 1);
            }
            sSlot[tid] = slot;
        }
    }
    __syncthreads();

    // ---- Touch: one thread per (t, a); priority max into table ----
    for (int item = tid; item < T * NA; item += 256) {
        int t = item / NA, a = item - t * NA;
        int p = sPack[t];
        if (!(p & 1)) continue;
        int slot = sSlot[t];
        int best = (p >> 1) & 0xF;
        if (a == best) {
            atomicMax(&sPri[slot * NA + a], 2 * t + 1);
            atomicMax(&sBest[slot * NA + a], 2 * t + 1);
        } else if ((p >> (5 + a)) & 1) {
            atomicMax(&sPri[slot * NA + a], 2 * t);
        }
    }
    __syncthreads();

    // ---- Resolve: one pass over table entries; C1 + C2 fused ----
    float corrNum = 0.f, corrDen = 0.f, lconfM = 0.f, maskCnt = 0.f;
    float lx = 0.f, ly = 0.f, lw = 0.f, lh = 0.f, lcls = 0.f;
    for (int it = tid; it < HSLOTS * NA; it += 256) {
        int slot = it / NA, a = it - slot * NA;
        int cell = sKey[slot];
        if (cell < 0) continue;
        int pm = sPri[it];
        if (pm < 0) continue;                   // (cell,a) untouched
        int bm = sBest[it];
        const float* pp = pred + ((size_t)(b * NA + a) * (NH * NW) + cell) * CH;
        float conf = pp[0];
        float bce0 = bcef(conf, 0.f);
        if (bm >= 0) {                          // masked: mask=1, tconf=1
            float cm = (float)(pm & 1);         // last-writer parity
            float cmf = cm - 1.f;               // 0 or -1
            float bce1 = bcef(conf, 1.f);
            corrNum += bce1 * cmf - bce0;
            corrDen += cmf - 1.f;
            lconfM += bce1;
            maskCnt += 1.f;
            int t = bm >> 1;                    // last best writer
            float dx = pp[1] - sTx[t], dy = pp[2] - sTy[t];
            float dw = pp[5] - sTw[t], dh = pp[4] - sTh[t];
            lx += dx * dx; ly += dy * dy; lw += dw * dw; lh += dh * dh;
            float q0 = pp[6], q1 = pp[7], q2 = pp[8], q3 = pp[9];
            float m = fmaxf(fmaxf(q0, q1), fmaxf(q2, q3));
            float lse = m + logf(expf(q0 - m) + expf(q1 - m) + expf(q2 - m) + expf(q3 - m));
            lcls += lse - pp[6 + sTl[t]];
        } else {                                // ignore-only: cmf = 0
            corrNum -= bce0;
            corrDen -= 1.f;
        }
    }

    float v;
    v = wredf(corrNum); if (lane == 0) sAccW[wave][0] = v;
    v = wredf(corrDen); if (lane == 0) sAccW[wave][1] = v;
    v = wredf(maskCnt); if (lane == 0) sAccW[wave][2] = v;
    v = wredf(lx);      if (lane == 0) sAccW[wave][3] = v;
    v = wredf(ly);      if (lane == 0) sAccW[wave][4] = v;
    v = wredf(lw);      if (lane == 0) sAccW[wave][5] = v;
    v = wredf(lh);      if (lane == 0) sAccW[wave][6] = v;
    v = wredf(lcls);    if (lane == 0) sAccW[wave][7] = v;
    v = wredf(lconfM);  if (lane == 0) sAccW[wave][8] = v;
    v = wredf(fGT);     if (lane == 0) sAccW[wave][9] = v;
    v = wredf(fCor);    if (lane == 0) sAccW[wave][10] = v;
    __syncthreads();
    if (tid < NSLOT) {
        float s = sAccW[0][tid] + sAccW[1][tid] + sAccW[2][tid] + sAccW[3][tid];
        scanPart[b * SCAN_STRIDE + tid] = s;
    }

    // ---- 16-block rendezvous; last block finalizes ----
    __syncthreads();
    if (tid == 0) {
        __threadfence();  // release scanPart
        unsigned int old = atomicAdd(doneCtr, 1u);
        sFlag = (old == (unsigned int)(nB - 1)) ? 1 : 0;
    }
    __syncthreads();
    if (sFlag) {
        __threadfence();  // acquire
        __shared__ double dR[2][4];
        __shared__ double dScan[NSLOT];
        double s0 = 0.0, np = 0.0;
        for (int i = tid; i < NBG; i += 256) {
            float2 p2 = bgPart[i];
            s0 += (double)p2.x; np += (double)p2.y;
        }
        s0 = wredd(s0); np = wredd(np);
        if (lane == 0) { dR[0][wave] = s0; dR[1][wave] = np; }
        if (tid < NSLOT) {
            double s = 0.0;
            for (int b2 = 0; b2 < nB; b2++) s += (double)scanPart[b2 * SCAN_STRIDE + tid];
            dScan[tid] = s;
        }
        __syncthreads();
        if (tid == 0) {
            double S0 = dR[0][0] + dR[0][1] + dR[0][2] + dR[0][3];
            double nProp = dR[1][0] + dR[1][1] + dR[1][2] + dR[1][3];
            double corrNum2 = dScan[0], corrDen2 = dScan[1], maskCnt2 = dScan[2];
            double lx2 = dScan[3], ly2 = dScan[4], lw2 = dScan[5], lh2 = dScan[6];
            double lcls2 = dScan[7], lconfM2 = dScan[8], nGT = dScan[9], nCor = dScan[10];

            double msum = fmax(maskCnt2, 1.0);
            double cden = fmax(totalCells + corrDen2, 1.0);
            double loss_conf = 1.25 * (S0 + corrNum2) / cden + lconfM2 / msum;
            double lx_ = lx2 / msum, ly_ = ly2 / msum, lw_ = lw2 / msum, lh_ = lh2 / msum;
            double lcls_ = (lcls2 / msum) / (double)nB;
            double coord = lx_ + ly_ + lw_ + lh_;
            double loss = coord + loss_conf + lcls_;
            double recall = (nGT > 0.0) ? nCor / fmax(nGT, 1.0) : 1.0;
            double precision = (nProp > 0.0) ? nCor / fmax(nProp, 1.0) : 1.0;

            out[0] = (float)loss;
            out[1] = (float)coord;
            out[2] = (float)loss_conf;
            out[3] = (float)lcls_;
            out[4] = (float)recall;
            out[5] = (float)precision;
        }
    }
}

extern "C" void kernel_launch(void* const* d_in, const int* in_sizes, int n_in,
                              void* d_out, int out_size, void* d_ws, size_t ws_size,
                              hipStream_t stream) {
    const float* pred = (const float*)d_in[0];
    const float* tgt = (const float*)d_in[1];
    const int* tsz = (const int*)d_in[2];
    int nB = in_sizes[2];
    int T = in_sizes[1] / (nB * TCOLS);
    long long total = (long long)nB * NA * NH * NW;
    int nCells = (int)total;

    // d_ws layout: [scanPart: nB*SCAN_STRIDE floats][bgPart: NBG float2][doneCtr]
    float* scanPart = (float*)d_ws;
    float2* bgPart = (float2*)((char*)d_ws + (size_t)nB * SCAN_STRIDE * sizeof(float));
    unsigned int* doneCtr =
        (unsigned int*)((char*)bgPart + (size_t)NBG * sizeof(float2));
    float* out = (float*)d_out;

    hipLaunchKernelGGL(k_bg, dim3(NBG), dim3(256), 0, stream, pred, bgPart,
                       doneCtr, nCells);
    hipLaunchKernelGGL(k_scanfin, dim3(nB), dim3(256), 0, stream, pred, tgt, tsz,
                       scanPart, bgPart, doneCtr, out, nB, T, (double)total);
}